// Round 1
// baseline (270.515 us; speedup 1.0000x reference)
//
#include <hip/hip_runtime.h>
#include <hip/hip_bf16.h>
#include <stdint.h>

// ---------- types ----------
typedef __bf16 bf16x8 __attribute__((ext_vector_type(8)));
typedef float  f32x4  __attribute__((ext_vector_type(4)));

__device__ __forceinline__ unsigned short f2bf(float f) {
  unsigned int u = __float_as_uint(f);
  u += 0x7FFF + ((u >> 16) & 1);          // round-to-nearest-even
  return (unsigned short)(u >> 16);
}

#define BM 128
#define BN 128
#define BK 32

#define GLOAD_LDS(gptr, ldsptr)                                                     \
  __builtin_amdgcn_global_load_lds(                                                 \
      (const __attribute__((address_space(1))) unsigned int*)(gptr),                \
      (__attribute__((address_space(3))) unsigned int*)(ldsptr), 16, 0, 0)

// C = A[M,K] * B[N,K]^T   (A,B bf16 row-major)
// mode 0: C bf16 [M,N] (+ sCz*z elements)
// mode 1: C bf16 transposed-per-batch: C[b][col][l], b=row>>11, l=row&2047 (vh^T)
// mode 2: C fp32 [M,N] * scale (+ sCz*z elements)
__global__ __launch_bounds__(256, 2) void gemm_bt(
    const unsigned short* __restrict__ A,
    const unsigned short* __restrict__ B,
    void* __restrict__ C,
    int M, int N, int K,
    long sAz, long sBz, long sCz,
    int mode, int causal_skip, int klimit, float scale)
{
  const int mt = blockIdx.x, nt = blockIdx.y, z = blockIdx.z;
  if (causal_skip && nt > mt) return;
  A += sAz * (long)z;
  B += sBz * (long)z;

  __shared__ __align__(16) unsigned short As[BM * BK];
  __shared__ __align__(16) unsigned short Bs[BN * BK];

  const int tid  = threadIdx.x;
  const int wave = tid >> 6;
  const int lane = tid & 63;
  const int wr = wave >> 1, wc = wave & 1;

  f32x4 acc[4][4];
#pragma unroll
  for (int i = 0; i < 4; ++i)
#pragma unroll
    for (int j = 0; j < 4; ++j) acc[i][j] = (f32x4){0.f, 0.f, 0.f, 0.f};

  int kiters = K / BK;
  if (klimit) { int kl = (mt + 1) * BM; if (kl < K) kiters = kl / BK; }

  // staging geometry: issue i covers LDS bytes [i*4096, i*4096+4096)
  // thread t: element offset i*2048 + t*8 -> row (eo>>5), col (eo&31)
  const int eo0 = tid * 8;
  const int r0 = eo0 >> 5, c0 = eo0 & 31;
  const int eo1 = 2048 + tid * 8;
  const int r1 = eo1 >> 5, c1 = eo1 & 31;
  const long aoff0 = (long)(mt * BM + r0) * K + c0;
  const long aoff1 = (long)(mt * BM + r1) * K + c1;
  const long boff0 = (long)(nt * BN + r0) * K + c0;
  const long boff1 = (long)(nt * BN + r1) * K + c1;
  const unsigned ldsw = wave * 1024;   // wave-uniform byte base within an issue

  for (int kt = 0; kt < kiters; ++kt) {
    const int k0 = kt * BK;
    GLOAD_LDS(A + aoff0 + k0, (char*)As + ldsw);
    GLOAD_LDS(A + aoff1 + k0, (char*)As + 4096 + ldsw);
    GLOAD_LDS(B + boff0 + k0, (char*)Bs + ldsw);
    GLOAD_LDS(B + boff1 + k0, (char*)Bs + 4096 + ldsw);
    __syncthreads();

    bf16x8 af[4], bfr[4];
#pragma unroll
    for (int i = 0; i < 4; ++i) {
      af[i]  = *(const bf16x8*)&As[(wr * 64 + i * 16 + (lane & 15)) * BK + ((lane >> 4) << 3)];
      bfr[i] = *(const bf16x8*)&Bs[(wc * 64 + i * 16 + (lane & 15)) * BK + ((lane >> 4) << 3)];
    }
#pragma unroll
    for (int mi = 0; mi < 4; ++mi)
#pragma unroll
      for (int ni = 0; ni < 4; ++ni)
        acc[mi][ni] = __builtin_amdgcn_mfma_f32_16x16x32_bf16(af[mi], bfr[ni], acc[mi][ni], 0, 0, 0);
    __syncthreads();
  }

  const int rb = mt * BM + wr * 64;
  const int cb = nt * BN + wc * 64;

  if (mode == 0) {
    unsigned short* Cb = (unsigned short*)C + sCz * (long)z;
#pragma unroll
    for (int mi = 0; mi < 4; ++mi)
#pragma unroll
      for (int ni = 0; ni < 4; ++ni) {
        const int row0 = rb + mi * 16 + ((lane >> 4) << 2);
        const int col  = cb + ni * 16 + (lane & 15);
#pragma unroll
        for (int j = 0; j < 4; ++j)
          Cb[(long)(row0 + j) * N + col] = f2bf(acc[mi][ni][j]);
      }
  } else if (mode == 1) {
    unsigned short* Cb = (unsigned short*)C;
#pragma unroll
    for (int mi = 0; mi < 4; ++mi)
#pragma unroll
      for (int ni = 0; ni < 4; ++ni) {
        const int row0 = rb + mi * 16 + ((lane >> 4) << 2);
        const int col  = cb + ni * 16 + (lane & 15);
#pragma unroll
        for (int j = 0; j < 4; ++j) {
          const int row = row0 + j;
          const int b = row >> 11, l = row & 2047;
          Cb[((long)b * N + col) * 2048 + l] = f2bf(acc[mi][ni][j]);
        }
      }
  } else {
    float* Cf = (float*)C + sCz * (long)z;
#pragma unroll
    for (int mi = 0; mi < 4; ++mi)
#pragma unroll
      for (int ni = 0; ni < 4; ++ni) {
        const int row0 = rb + mi * 16 + ((lane >> 4) << 2);
        const int col  = cb + ni * 16 + (lane & 15);
#pragma unroll
        for (int j = 0; j < 4; ++j)
          Cf[(long)(row0 + j) * N + col] = acc[mi][ni][j] * scale;
      }
  }
}

// fp32 -> bf16 (RNE), vectorized x4
__global__ __launch_bounds__(256) void f32_to_bf16_vec(
    const float* __restrict__ src, unsigned short* __restrict__ dst, long nvec4)
{
  long i = (long)blockIdx.x * 256 + threadIdx.x;
  const long stride = (long)gridDim.x * 256;
  for (; i < nvec4; i += stride) {
    float4 v = ((const float4*)src)[i];
    ushort4 o;
    o.x = f2bf(v.x); o.y = f2bf(v.y); o.z = f2bf(v.z); o.w = f2bf(v.w);
    ((ushort4*)dst)[i] = o;
  }
}

// causal row softmax: S fp32 [B,L,L] -> P bf16 [B,L,L], zeros above diagonal
__global__ __launch_bounds__(256) void softmax_causal(
    const float* __restrict__ S, unsigned short* __restrict__ P, int L)
{
  const int r = blockIdx.x;              // 0..B*L-1
  const int b = r >> 11, q = r & 2047;
  const float* srow = S + ((long)b * L + q) * L;
  unsigned short* prow = P + ((long)b * L + q) * L;
  const int len = q + 1;
  const int tid = threadIdx.x, lane = tid & 63, wave = tid >> 6;
  __shared__ float red[8];

  float m = -3.4e38f;
  for (int i = tid; i < len; i += 256) m = fmaxf(m, srow[i]);
#pragma unroll
  for (int o = 32; o; o >>= 1) m = fmaxf(m, __shfl_xor(m, o));
  if (lane == 0) red[wave] = m;
  __syncthreads();
  m = fmaxf(fmaxf(red[0], red[1]), fmaxf(red[2], red[3]));

  float s = 0.f;
  for (int i = tid; i < len; i += 256) s += __expf(srow[i] - m);
#pragma unroll
  for (int o = 32; o; o >>= 1) s += __shfl_xor(s, o);
  if (lane == 0) red[4 + wave] = s;
  __syncthreads();
  s = (red[4] + red[5]) + (red[6] + red[7]);
  const float inv = 1.f / s;

  for (int i = tid; i < L; i += 256) {
    unsigned short o16 = 0;
    if (i < len) o16 = f2bf(__expf(srow[i] - m) * inv);
    prow[i] = o16;
  }
}

extern "C" void kernel_launch(void* const* d_in, const int* in_sizes, int n_in,
                              void* d_out, int out_size, void* d_ws, size_t ws_size,
                              hipStream_t stream) {
  const float* q  = (const float*)d_in[0];
  const float* k  = (const float*)d_in[1];
  const float* v  = (const float*)d_in[2];
  const float* Wq = (const float*)d_in[3];
  const float* Wk = (const float*)d_in[4];
  const float* Wv = (const float*)d_in[5];
  const float* Wp = (const float*)d_in[6];
  float* out = (float*)d_out;

  const long Mtot = 8192;        // B*L
  const long D    = 1024;
  const long L    = 2048;
  const long ND   = Mtot * D;    // 8,388,608 elements
  const long NS   = 4L * L * L;  // 16,777,216 elements

  char* ws = (char*)d_ws;
  unsigned short* qh    = (unsigned short*)ws;                 // 16 MB
  unsigned short* kh    = qh  + ND;                            // 16 MB
  unsigned short* vhT   = kh  + ND;                            // 16 MB
  unsigned short* P     = vhT + ND;                            // 32 MB
  unsigned short* ybf   = P   + NS;                            // 16 MB
  unsigned short* wbf   = ybf + ND;                            // 8 MB (4 weights)
  float*          S     = (float*)(wbf + 4L * D * D);          // 64 MB fp32
  unsigned short* qkvbf = (unsigned short*)S;                  // aliases S (dead before S written)

  // 1) convert inputs + weights to bf16
  f32_to_bf16_vec<<<2048, 256, 0, stream>>>(q,  qkvbf,           ND / 4);
  f32_to_bf16_vec<<<2048, 256, 0, stream>>>(k,  qkvbf + ND,      ND / 4);
  f32_to_bf16_vec<<<2048, 256, 0, stream>>>(v,  qkvbf + 2 * ND,  ND / 4);
  f32_to_bf16_vec<<<512,  256, 0, stream>>>(Wq, wbf,                 D * D / 4);
  f32_to_bf16_vec<<<512,  256, 0, stream>>>(Wk, wbf + D * D,         D * D / 4);
  f32_to_bf16_vec<<<512,  256, 0, stream>>>(Wv, wbf + 2 * D * D,     D * D / 4);
  f32_to_bf16_vec<<<512,  256, 0, stream>>>(Wp, wbf + 3 * D * D,     D * D / 4);

  // 2) projections: qh = q*Wq^T, kh = k*Wk^T, vhT = (v*Wv^T)^T per batch
  gemm_bt<<<dim3(64, 8, 1), 256, 0, stream>>>(qkvbf,          wbf,             qh,
      8192, 1024, 1024, 0, 0, 0, 0, 0, 0, 1.0f);
  gemm_bt<<<dim3(64, 8, 1), 256, 0, stream>>>(qkvbf + ND,     wbf + D * D,     kh,
      8192, 1024, 1024, 0, 0, 0, 0, 0, 0, 1.0f);
  gemm_bt<<<dim3(64, 8, 1), 256, 0, stream>>>(qkvbf + 2 * ND, wbf + 2 * D * D, vhT,
      8192, 1024, 1024, 0, 0, 0, 1, 0, 0, 1.0f);

  // 3) S = qh * kh^T * 0.125 per batch, causal tile skip
  gemm_bt<<<dim3(16, 16, 4), 256, 0, stream>>>(qh, kh, S,
      2048, 2048, 1024, L * D, L * D, L * L, 2, 1, 0, 0.125f);

  // 4) causal softmax -> P (bf16, zero-filled above diagonal)
  softmax_causal<<<8192, 256, 0, stream>>>(S, P, 2048);

  // 5) Y = P * vh  (as P * vhT^T), causal K-limit
  gemm_bt<<<dim3(16, 8, 4), 256, 0, stream>>>(P, vhT, ybf,
      2048, 1024, 2048, L * L, D * L, L * D, 0, 0, 1, 1.0f);

  // 6) out = Y * Wproj^T (fp32)
  gemm_bt<<<dim3(64, 8, 1), 256, 0, stream>>>(ybf, wbf + 3 * D * D, out,
      8192, 1024, 1024, 0, 0, 0, 2, 0, 0, 1.0f);
}

// Round 2
// 250.442 us; speedup vs baseline: 1.0802x; 1.0802x over previous
//
#include <hip/hip_runtime.h>
#include <hip/hip_bf16.h>
#include <stdint.h>

typedef __bf16 bf16x8 __attribute__((ext_vector_type(8)));
typedef float  f32x4  __attribute__((ext_vector_type(4)));

__device__ __forceinline__ unsigned short f2bf(float f) {
  unsigned int u = __float_as_uint(f);
  u += 0x7FFF + ((u >> 16) & 1);          // round-to-nearest-even
  return (unsigned short)(u >> 16);
}

#define BM 128
#define BN 128
#define BK 32

#define GLOAD_LDS(gptr, ldsptr)                                                     \
  __builtin_amdgcn_global_load_lds(                                                 \
      (const __attribute__((address_space(1))) unsigned int*)(gptr),                \
      (__attribute__((address_space(3))) unsigned int*)(ldsptr), 16, 0, 0)

// C = A[M,K] * B[N,K]^T   (A,B bf16 row-major)
// mode 0: C bf16 [M,N] (+ sCz*z)
// mode 1: C bf16 transposed-per-batch: C[b][col][l], b=row>>11, l=row&2047  (+ sCz*z)
// mode 2: C fp32 [M,N] * scale (+ sCz*z)
// mode 3: merged projections: z<2 -> mode 0, z==2 -> mode 1
__global__ __launch_bounds__(256, 2) void gemm_bt(
    const unsigned short* __restrict__ A,
    const unsigned short* __restrict__ B,
    void* __restrict__ C,
    int M, int N, int K, int ntiles,
    long sAz, long sBz, long sCz,
    int mode, int causal_skip, int klimit, float scale)
{
  // ---- bijective XCD chunk swizzle (m204) on mt-major flat tile id ----
  const int nwg  = gridDim.x;
  const int orig = blockIdx.x;
  const int qq = nwg >> 3, rr = nwg & 7, xc = orig & 7, oo = orig >> 3;
  const int wg = (xc < rr ? xc * (qq + 1) : rr * (qq + 1) + (xc - rr) * qq) + oo;
  const int mt = wg / ntiles, nt = wg % ntiles;
  const int z  = blockIdx.y;
  if (causal_skip && nt > mt) return;
  const int emode = (mode == 3) ? (z == 2 ? 1 : 0) : mode;

  A += sAz * (long)z;
  B += sBz * (long)z;

  // double-buffered LDS: 2 x (8KB A + 8KB B) = 32KB
  __shared__ __align__(16) unsigned short As[2][BM * BK];
  __shared__ __align__(16) unsigned short Bs[2][BN * BK];

  const int tid  = threadIdx.x;
  const int wave = tid >> 6;
  const int lane = tid & 63;
  const int wr = wave >> 1, wc = wave & 1;

  f32x4 acc[4][4];
#pragma unroll
  for (int i = 0; i < 4; ++i)
#pragma unroll
    for (int j = 0; j < 4; ++j) acc[i][j] = (f32x4){0.f, 0.f, 0.f, 0.f};

  int kiters = K / BK;
  if (klimit) { int kl = (mt + 1) * BM; if (kl < K) kiters = kl / BK; }

  // ---- staging geometry (XOR-swizzled source, linear LDS dest; rule 21) ----
  // issue i covers LDS bytes [i*4096, i*4096+4096): thread t writes 16B at t*16
  // -> LDS row r = i*64 + (t>>2), 16B slot s = t&3.
  // swizzle: LDS slot s of row r holds global col-slot (s ^ ((r>>1)&3)).
  const int r0 = tid >> 2, s0 = tid & 3;
  const int c0 = ((s0 ^ ((r0 >> 1) & 3)) << 3);            // element col, issue 0
  const int r1 = r0 + 64;
  const int c1 = ((s0 ^ ((r1 >> 1) & 3)) << 3);            // element col, issue 1
  const long aoff0 = (long)(mt * BM + r0) * K + c0;
  const long aoff1 = (long)(mt * BM + r1) * K + c1;
  const long boff0 = (long)(nt * BN + r0) * K + c0;
  const long boff1 = (long)(nt * BN + r1) * K + c1;
  const unsigned ldsw = wave * 1024;                       // wave-uniform base in an issue

#define STAGE(bi, k0)                                                     \
  do {                                                                    \
    GLOAD_LDS(A + aoff0 + (k0), (char*)&As[bi][0]    + ldsw);             \
    GLOAD_LDS(A + aoff1 + (k0), (char*)&As[bi][2048] + ldsw);             \
    GLOAD_LDS(B + boff0 + (k0), (char*)&Bs[bi][0]    + ldsw);             \
    GLOAD_LDS(B + boff1 + (k0), (char*)&Bs[bi][2048] + ldsw);             \
  } while (0)

  // prologue: stage tile 0 into buffer 0
  STAGE(0, 0);

  int cur = 0;
  for (int kt = 0; kt < kiters; ++kt) {
    if (kt + 1 < kiters) {
      STAGE(cur ^ 1, (kt + 1) * BK);
      asm volatile("s_waitcnt vmcnt(4)" ::: "memory");   // oldest 4 (= buf[cur]) landed
    } else {
      asm volatile("s_waitcnt vmcnt(0)" ::: "memory");
    }
    __builtin_amdgcn_s_barrier();
    asm volatile("" ::: "memory");

    bf16x8 af[4], bfr[4];
#pragma unroll
    for (int i = 0; i < 4; ++i) {
      const int ar = wr * 64 + i * 16 + (lane & 15);
      const int as = ((lane >> 4) ^ ((ar >> 1) & 3)) << 3;
      af[i] = *(const bf16x8*)&As[cur][ar * BK + as];
      const int br = wc * 64 + i * 16 + (lane & 15);
      const int bs = ((lane >> 4) ^ ((br >> 1) & 3)) << 3;
      bfr[i] = *(const bf16x8*)&Bs[cur][br * BK + bs];
    }
#pragma unroll
    for (int mi = 0; mi < 4; ++mi)
#pragma unroll
      for (int ni = 0; ni < 4; ++ni)
        acc[mi][ni] = __builtin_amdgcn_mfma_f32_16x16x32_bf16(af[mi], bfr[ni], acc[mi][ni], 0, 0, 0);

    asm volatile("" ::: "memory");
    __builtin_amdgcn_s_barrier();   // all waves done reading buf[cur] -> overwrite ok
    cur ^= 1;
  }
#undef STAGE

  const int rb = mt * BM + wr * 64;
  const int cb = nt * BN + wc * 64;

  if (emode == 0) {
    unsigned short* Cb = (unsigned short*)C + sCz * (long)z;
#pragma unroll
    for (int mi = 0; mi < 4; ++mi)
#pragma unroll
      for (int ni = 0; ni < 4; ++ni) {
        const int row0 = rb + mi * 16 + ((lane >> 4) << 2);
        const int col  = cb + ni * 16 + (lane & 15);
#pragma unroll
        for (int j = 0; j < 4; ++j)
          Cb[(long)(row0 + j) * N + col] = f2bf(acc[mi][ni][j]);
      }
  } else if (emode == 1) {
    unsigned short* Cb = (unsigned short*)C + sCz * (long)z;
#pragma unroll
    for (int mi = 0; mi < 4; ++mi)
#pragma unroll
      for (int ni = 0; ni < 4; ++ni) {
        const int row0 = rb + mi * 16 + ((lane >> 4) << 2);
        const int col  = cb + ni * 16 + (lane & 15);
#pragma unroll
        for (int j = 0; j < 4; ++j) {
          const int row = row0 + j;
          const int b = row >> 11, l = row & 2047;
          Cb[((long)b * N + col) * 2048 + l] = f2bf(acc[mi][ni][j]);
        }
      }
  } else {
    float* Cf = (float*)C + sCz * (long)z;
#pragma unroll
    for (int mi = 0; mi < 4; ++mi)
#pragma unroll
      for (int ni = 0; ni < 4; ++ni) {
        const int row0 = rb + mi * 16 + ((lane >> 4) << 2);
        const int col  = cb + ni * 16 + (lane & 15);
#pragma unroll
        for (int j = 0; j < 4; ++j)
          Cf[(long)(row0 + j) * N + col] = acc[mi][ni][j] * scale;
      }
  }
}

// fp32 -> bf16 (RNE), vectorized x4
__global__ __launch_bounds__(256) void f32_to_bf16_vec(
    const float* __restrict__ src, unsigned short* __restrict__ dst, long nvec4)
{
  long i = (long)blockIdx.x * 256 + threadIdx.x;
  const long stride = (long)gridDim.x * 256;
  for (; i < nvec4; i += stride) {
    float4 v = ((const float4*)src)[i];
    ushort4 o;
    o.x = f2bf(v.x); o.y = f2bf(v.y); o.z = f2bf(v.z); o.w = f2bf(v.w);
    ((ushort4*)dst)[i] = o;
  }
}

// causal row softmax: S fp32 [B,L,L] -> P bf16 [B,L,L], zeros above diagonal
__global__ __launch_bounds__(256) void softmax_causal(
    const float* __restrict__ S, unsigned short* __restrict__ P, int L)
{
  const int r = blockIdx.x;              // 0..B*L-1
  const int b = r >> 11, q = r & 2047;
  const float* srow = S + ((long)b * L + q) * L;
  unsigned short* prow = P + ((long)b * L + q) * L;
  const int len = q + 1;
  const int tid = threadIdx.x, lane = tid & 63, wave = tid >> 6;
  __shared__ float red[8];

  float m = -3.4e38f;
  for (int i = tid; i < len; i += 256) m = fmaxf(m, srow[i]);
#pragma unroll
  for (int o = 32; o; o >>= 1) m = fmaxf(m, __shfl_xor(m, o));
  if (lane == 0) red[wave] = m;
  __syncthreads();
  m = fmaxf(fmaxf(red[0], red[1]), fmaxf(red[2], red[3]));

  float s = 0.f;
  for (int i = tid; i < len; i += 256) s += __expf(srow[i] - m);
#pragma unroll
  for (int o = 32; o; o >>= 1) s += __shfl_xor(s, o);
  if (lane == 0) red[4 + wave] = s;
  __syncthreads();
  s = (red[4] + red[5]) + (red[6] + red[7]);
  const float inv = 1.f / s;

  for (int i = tid; i < L; i += 256) {
    unsigned short o16 = 0;
    if (i < len) o16 = f2bf(__expf(srow[i] - m) * inv);
    prow[i] = o16;
  }
}

extern "C" void kernel_launch(void* const* d_in, const int* in_sizes, int n_in,
                              void* d_out, int out_size, void* d_ws, size_t ws_size,
                              hipStream_t stream) {
  const float* q  = (const float*)d_in[0];
  const float* k  = (const float*)d_in[1];
  const float* v  = (const float*)d_in[2];
  const float* Wq = (const float*)d_in[3];
  const float* Wk = (const float*)d_in[4];
  const float* Wv = (const float*)d_in[5];
  const float* Wp = (const float*)d_in[6];
  float* out = (float*)d_out;

  const long D    = 1024;
  const long L    = 2048;
  const long ND   = 8192 * D;    // B*L*D elements
  const long NS   = 4L * L * L;

  char* ws = (char*)d_ws;
  unsigned short* qh    = (unsigned short*)ws;                 // 16 MB (z=0)
  unsigned short* kh    = qh  + ND;                            // 16 MB (z=1)
  unsigned short* vhT   = kh  + ND;                            // 16 MB (z=2, transposed)
  unsigned short* P     = vhT + ND;                            // 32 MB
  unsigned short* ybf   = P   + NS;                            // 16 MB
  unsigned short* wbf   = ybf + ND;                            // 8 MB (4 weights)
  float*          S     = (float*)(wbf + 4L * D * D);          // 64 MB fp32
  unsigned short* qkvbf = (unsigned short*)S;                  // aliases S (dead before S written)

  // 1) convert inputs + weights to bf16
  f32_to_bf16_vec<<<2048, 256, 0, stream>>>(q,  qkvbf,           ND / 4);
  f32_to_bf16_vec<<<2048, 256, 0, stream>>>(k,  qkvbf + ND,      ND / 4);
  f32_to_bf16_vec<<<2048, 256, 0, stream>>>(v,  qkvbf + 2 * ND,  ND / 4);
  f32_to_bf16_vec<<<512,  256, 0, stream>>>(Wq, wbf,                 D * D / 4);
  f32_to_bf16_vec<<<512,  256, 0, stream>>>(Wk, wbf + D * D,         D * D / 4);
  f32_to_bf16_vec<<<512,  256, 0, stream>>>(Wv, wbf + 2 * D * D,     D * D / 4);
  f32_to_bf16_vec<<<512,  256, 0, stream>>>(Wp, wbf + 3 * D * D,     D * D / 4);

  // 2) merged projections (z=3): qh, kh (mode 0) and vhT (mode 1)
  gemm_bt<<<dim3(512, 3), 256, 0, stream>>>(qkvbf, wbf, qh,
      8192, 1024, 1024, 8, ND, D * D, ND, 3, 0, 0, 1.0f);

  // 3) S = qh * kh^T * 0.125 per batch, causal tile skip
  gemm_bt<<<dim3(256, 4), 256, 0, stream>>>(qh, kh, S,
      2048, 2048, 1024, 16, L * D, L * D, L * L, 2, 1, 0, 0.125f);

  // 4) causal softmax -> P (bf16, zero-filled above diagonal)
  softmax_causal<<<8192, 256, 0, stream>>>(S, P, 2048);

  // 5) Y = P * vh  (as P * vhT^T), causal K-limit
  gemm_bt<<<dim3(128, 4), 256, 0, stream>>>(P, vhT, ybf,
      2048, 1024, 2048, 8, L * L, D * L, L * D, 0, 0, 1, 1.0f);

  // 6) out = Y * Wproj^T (fp32)
  gemm_bt<<<dim3(512, 1), 256, 0, stream>>>(ybf, wbf + 3 * D * D, out,
      8192, 1024, 1024, 8, 0, 0, 0, 2, 0, 0, 1.0f);
}

// Round 3
// 238.248 us; speedup vs baseline: 1.1354x; 1.0512x over previous
//
#include <hip/hip_runtime.h>
#include <hip/hip_bf16.h>
#include <stdint.h>

typedef __bf16 bf16x8 __attribute__((ext_vector_type(8)));
typedef float  f32x4  __attribute__((ext_vector_type(4)));
typedef unsigned short ushort8v __attribute__((ext_vector_type(8)));

__device__ __forceinline__ unsigned short f2bf(float f) {
  unsigned int u = __float_as_uint(f);
  u += 0x7FFF + ((u >> 16) & 1);          // round-to-nearest-even
  return (unsigned short)(u >> 16);
}

#define BM 128
#define BN 128
#define BK 32

#define GLOAD_LDS(gptr, ldsptr)                                                     \
  __builtin_amdgcn_global_load_lds(                                                 \
      (const __attribute__((address_space(1))) unsigned int*)(gptr),                \
      (__attribute__((address_space(3))) unsigned int*)(ldsptr), 16, 0, 0)

// C = A[M,K] * B[N,K]^T   (A,B bf16 row-major)
// mode 0: C bf16 [M,N] (+ sCz*z)
// mode 1: C bf16 transposed-per-batch: C[b][col][l], b=row>>11, l=row&2047  (+ sCz*z)
// mode 2: C fp32 [M,N] * scale (+ sCz*z)
// mode 3: merged projections: z<2 -> mode 0, z==2 -> mode 1
__global__ __launch_bounds__(256, 3) void gemm_bt(
    const unsigned short* __restrict__ A,
    const unsigned short* __restrict__ B,
    void* __restrict__ C,
    int M, int N, int K, int ntiles,
    long sAz, long sBz, long sCz,
    int mode, int causal_skip, int klimit, float scale)
{
  // ---- bijective XCD chunk swizzle (m204) on mt-major flat tile id ----
  const int nwg  = gridDim.x;
  const int orig = blockIdx.x;
  const int qq = nwg >> 3, rr = nwg & 7, xc = orig & 7, oo = orig >> 3;
  const int wg = (xc < rr ? xc * (qq + 1) : rr * (qq + 1) + (xc - rr) * qq) + oo;
  const int mt = wg / ntiles, nt = wg % ntiles;
  const int z  = blockIdx.y;
  if (causal_skip && nt > mt) return;
  const int emode = (mode == 3) ? (z == 2 ? 1 : 0) : mode;

  A += sAz * (long)z;
  B += sBz * (long)z;

  // triple-buffered LDS: 3 x (8KB A + 8KB B) = 48KB -> 3 blocks/CU
  __shared__ __align__(16) unsigned short As[3][BM * BK];
  __shared__ __align__(16) unsigned short Bs[3][BN * BK];

  const int tid  = threadIdx.x;
  const int wave = tid >> 6;
  const int lane = tid & 63;
  const int wr = wave >> 1, wc = wave & 1;

  f32x4 acc[4][4];
#pragma unroll
  for (int i = 0; i < 4; ++i)
#pragma unroll
    for (int j = 0; j < 4; ++j) acc[i][j] = (f32x4){0.f, 0.f, 0.f, 0.f};

  int kiters = K / BK;
  if (klimit) { int kl = (mt + 1) * BM; if (kl < K) kiters = kl / BK; }

  // ---- staging geometry (XOR-swizzled source, linear LDS dest; rule 21) ----
  // issue i covers LDS bytes [i*4096, i*4096+4096): thread t writes 16B at t*16
  // -> LDS row r = i*64 + (t>>2), 16B slot s = t&3.
  // swizzle: LDS slot s of row r holds global col-slot (s ^ ((r>>1)&3)).
  const int r0 = tid >> 2, s0 = tid & 3;
  const int c0 = ((s0 ^ ((r0 >> 1) & 3)) << 3);            // element col, issue 0
  const int r1 = r0 + 64;
  const int c1 = ((s0 ^ ((r1 >> 1) & 3)) << 3);            // element col, issue 1
  const long aoff0 = (long)(mt * BM + r0) * K + c0;
  const long aoff1 = (long)(mt * BM + r1) * K + c1;
  const long boff0 = (long)(nt * BN + r0) * K + c0;
  const long boff1 = (long)(nt * BN + r1) * K + c1;
  const unsigned ldsw = wave * 1024;                       // wave-uniform base in an issue

#define STAGE(bi, k0)                                                     \
  do {                                                                    \
    GLOAD_LDS(A + aoff0 + (k0), (char*)&As[bi][0]    + ldsw);             \
    GLOAD_LDS(A + aoff1 + (k0), (char*)&As[bi][2048] + ldsw);             \
    GLOAD_LDS(B + boff0 + (k0), (char*)&Bs[bi][0]    + ldsw);             \
    GLOAD_LDS(B + boff1 + (k0), (char*)&Bs[bi][2048] + ldsw);             \
  } while (0)

  // prologue: stage tiles 0 and 1
  STAGE(0, 0);
  if (kiters > 1) STAGE(1, BK);

  int cur = 0;
  for (int kt = 0; kt < kiters; ++kt) {
    const int rem = kiters - 1 - kt;       // tiles still ahead of this one
    if (rem >= 2) {
      int sb = cur + 2; if (sb >= 3) sb -= 3;
      STAGE(sb, (kt + 2) * BK);
      asm volatile("s_waitcnt vmcnt(8)" ::: "memory");   // tiles kt+1,kt+2 in flight
    } else if (rem == 1) {
      asm volatile("s_waitcnt vmcnt(4)" ::: "memory");   // tile kt+1 in flight
    } else {
      asm volatile("s_waitcnt vmcnt(0)" ::: "memory");   // epilogue drain
    }
    __builtin_amdgcn_s_barrier();
    asm volatile("" ::: "memory");

    bf16x8 af[4], bfr[4];
#pragma unroll
    for (int i = 0; i < 4; ++i) {
      const int ar = wr * 64 + i * 16 + (lane & 15);
      const int as = ((lane >> 4) ^ ((ar >> 1) & 3)) << 3;
      af[i] = *(const bf16x8*)&As[cur][ar * BK + as];
      const int br = wc * 64 + i * 16 + (lane & 15);
      const int bs = ((lane >> 4) ^ ((br >> 1) & 3)) << 3;
      bfr[i] = *(const bf16x8*)&Bs[cur][br * BK + bs];
    }
#pragma unroll
    for (int mi = 0; mi < 4; ++mi)
#pragma unroll
      for (int ni = 0; ni < 4; ++ni)
        acc[mi][ni] = __builtin_amdgcn_mfma_f32_16x16x32_bf16(af[mi], bfr[ni], acc[mi][ni], 0, 0, 0);

    asm volatile("" ::: "memory");
    __builtin_amdgcn_s_barrier();   // all waves done reading buf[cur] -> overwrite ok
    cur = (cur == 2) ? 0 : cur + 1;
  }
#undef STAGE

  const int rb = mt * BM + wr * 64;
  const int cb = nt * BN + wc * 64;

  if (emode == 0) {
    unsigned short* Cb = (unsigned short*)C + sCz * (long)z;
#pragma unroll
    for (int mi = 0; mi < 4; ++mi)
#pragma unroll
      for (int ni = 0; ni < 4; ++ni) {
        const int row0 = rb + mi * 16 + ((lane >> 4) << 2);
        const int col  = cb + ni * 16 + (lane & 15);
#pragma unroll
        for (int j = 0; j < 4; ++j)
          Cb[(long)(row0 + j) * N + col] = f2bf(acc[mi][ni][j]);
      }
  } else if (emode == 1) {
    unsigned short* Cb = (unsigned short*)C + sCz * (long)z;
#pragma unroll
    for (int mi = 0; mi < 4; ++mi)
#pragma unroll
      for (int ni = 0; ni < 4; ++ni) {
        const int row0 = rb + mi * 16 + ((lane >> 4) << 2);
        const int col  = cb + ni * 16 + (lane & 15);
#pragma unroll
        for (int j = 0; j < 4; ++j) {
          const int row = row0 + j;
          const int b = row >> 11, l = row & 2047;
          Cb[((long)b * N + col) * 2048 + l] = f2bf(acc[mi][ni][j]);
        }
      }
  } else {
    float* Cf = (float*)C + sCz * (long)z;
#pragma unroll
    for (int mi = 0; mi < 4; ++mi)
#pragma unroll
      for (int ni = 0; ni < 4; ++ni) {
        const int row0 = rb + mi * 16 + ((lane >> 4) << 2);
        const int col  = cb + ni * 16 + (lane & 15);
#pragma unroll
        for (int j = 0; j < 4; ++j)
          Cf[(long)(row0 + j) * N + col] = acc[mi][ni][j] * scale;
      }
  }
}

// merged fp32 -> bf16 (RNE) for q,k,v (512 blocks each) + 4 weights (64 blocks each)
__global__ __launch_bounds__(256) void convert_all(
    const float* __restrict__ q, const float* __restrict__ k, const float* __restrict__ v,
    const float* __restrict__ wq, const float* __restrict__ wk,
    const float* __restrict__ wv, const float* __restrict__ wp,
    unsigned short* __restrict__ qkv, unsigned short* __restrict__ wb)
{
  const long NQ = 8192L * 1024 / 4;   // float4 count per qkv tensor
  const long NW = 1024L * 1024 / 4;   // float4 count per weight
  const int blk = blockIdx.x;
  const float* src; unsigned short* dst; long n; int nb, bb;
  if (blk < 1536) {
    const int s = blk >> 9;
    src = (s == 0) ? q : (s == 1) ? k : v;
    dst = qkv + (long)s * (8192L * 1024);
    n = NQ; nb = 512; bb = blk & 511;
  } else {
    const int s = (blk - 1536) >> 6;
    src = (s == 0) ? wq : (s == 1) ? wk : (s == 2) ? wv : wp;
    dst = wb + (long)s * (1024L * 1024);
    n = NW; nb = 64; bb = (blk - 1536) & 63;
  }
  for (long i = (long)bb * 256 + threadIdx.x; i < n; i += (long)nb * 256) {
    float4 x = ((const float4*)src)[i];
    ushort4 o;
    o.x = f2bf(x.x); o.y = f2bf(x.y); o.z = f2bf(x.z); o.w = f2bf(x.w);
    ((ushort4*)dst)[i] = o;
  }
}

// single-pass causal row softmax: S fp32 [B,L,L] -> P bf16, zeros above diagonal
// one block per row; each thread owns 8 contiguous elements (registers).
__global__ __launch_bounds__(256) void softmax_causal(
    const float* __restrict__ S, unsigned short* __restrict__ P, int L)
{
  const int r = blockIdx.x;              // 0..B*L-1
  const int b = r >> 11, q = r & 2047;
  const float* srow = S + ((long)b * L + q) * L;
  unsigned short* prow = P + ((long)b * L + q) * L;
  const int len = q + 1;
  const int tid = threadIdx.x, lane = tid & 63, wave = tid >> 6;
  const int base = tid * 8;
  __shared__ float red[8];

  float4 x0 = ((const float4*)srow)[tid * 2];
  float4 x1 = ((const float4*)srow)[tid * 2 + 1];
  float vv[8] = {x0.x, x0.y, x0.z, x0.w, x1.x, x1.y, x1.z, x1.w};

  float m = -3.4e38f;
#pragma unroll
  for (int i = 0; i < 8; ++i) if (base + i < len) m = fmaxf(m, vv[i]);
#pragma unroll
  for (int o = 32; o; o >>= 1) m = fmaxf(m, __shfl_xor(m, o));
  if (lane == 0) red[wave] = m;
  __syncthreads();
  m = fmaxf(fmaxf(red[0], red[1]), fmaxf(red[2], red[3]));

  float p[8], s = 0.f;
#pragma unroll
  for (int i = 0; i < 8; ++i) {
    p[i] = (base + i < len) ? __expf(vv[i] - m) : 0.f;
    s += p[i];
  }
#pragma unroll
  for (int o = 32; o; o >>= 1) s += __shfl_xor(s, o);
  if (lane == 0) red[4 + wave] = s;
  __syncthreads();
  s = (red[4] + red[5]) + (red[6] + red[7]);
  const float inv = 1.f / s;

  ushort8v o16;
#pragma unroll
  for (int i = 0; i < 8; ++i) o16[i] = f2bf(p[i] * inv);
  *(ushort8v*)(prow + base) = o16;
}

extern "C" void kernel_launch(void* const* d_in, const int* in_sizes, int n_in,
                              void* d_out, int out_size, void* d_ws, size_t ws_size,
                              hipStream_t stream) {
  const float* q  = (const float*)d_in[0];
  const float* k  = (const float*)d_in[1];
  const float* v  = (const float*)d_in[2];
  const float* Wq = (const float*)d_in[3];
  const float* Wk = (const float*)d_in[4];
  const float* Wv = (const float*)d_in[5];
  const float* Wp = (const float*)d_in[6];
  float* out = (float*)d_out;

  const long D    = 1024;
  const long L    = 2048;
  const long ND   = 8192 * D;    // B*L*D elements
  const long NS   = 4L * L * L;

  char* ws = (char*)d_ws;
  unsigned short* qh    = (unsigned short*)ws;                 // 16 MB (z=0)
  unsigned short* kh    = qh  + ND;                            // 16 MB (z=1)
  unsigned short* vhT   = kh  + ND;                            // 16 MB (z=2, transposed)
  unsigned short* P     = vhT + ND;                            // 32 MB
  unsigned short* ybf   = P   + NS;                            // 16 MB
  unsigned short* wbf   = ybf + ND;                            // 8 MB (4 weights)
  float*          S     = (float*)(wbf + 4L * D * D);          // 64 MB fp32
  unsigned short* qkvbf = (unsigned short*)S;                  // aliases S (dead before S written)

  // 1) convert inputs + weights to bf16 (single dispatch)
  convert_all<<<1792, 256, 0, stream>>>(q, k, v, Wq, Wk, Wv, Wp, qkvbf, wbf);

  // 2) merged projections (z=3): qh, kh (mode 0) and vhT (mode 1)
  gemm_bt<<<dim3(512, 3), 256, 0, stream>>>(qkvbf, wbf, qh,
      8192, 1024, 1024, 8, ND, D * D, ND, 3, 0, 0, 1.0f);

  // 3) S = qh * kh^T * 0.125 per batch, causal tile skip
  gemm_bt<<<dim3(256, 4), 256, 0, stream>>>(qh, kh, S,
      2048, 2048, 1024, 16, L * D, L * D, L * L, 2, 1, 0, 0.125f);

  // 4) causal softmax -> P (bf16, zero-filled above diagonal)
  softmax_causal<<<8192, 256, 0, stream>>>(S, P, 2048);

  // 5) Y = P * vh  (as P * vhT^T), causal K-limit
  gemm_bt<<<dim3(128, 4), 256, 0, stream>>>(P, vhT, ybf,
      2048, 1024, 2048, 8, L * L, D * L, L * D, 0, 0, 1, 1.0f);

  // 6) out = Y * Wproj^T (fp32)
  gemm_bt<<<dim3(512, 1), 256, 0, stream>>>(ybf, wbf + 3 * D * D, out,
      8192, 1024, 1024, 8, 0, 0, 0, 2, 0, 0, 1.0f);
}

// Round 4
// 234.048 us; speedup vs baseline: 1.1558x; 1.0179x over previous
//
#include <hip/hip_runtime.h>
#include <hip/hip_bf16.h>
#include <stdint.h>

typedef __bf16 bf16x8 __attribute__((ext_vector_type(8)));
typedef float  f32x4  __attribute__((ext_vector_type(4)));
typedef unsigned short ushort8v __attribute__((ext_vector_type(8)));

__device__ __forceinline__ unsigned short f2bf(float f) {
  unsigned int u = __float_as_uint(f);
  u += 0x7FFF + ((u >> 16) & 1);          // round-to-nearest-even
  return (unsigned short)(u >> 16);
}

#define GLOAD_LDS(gptr, ldsptr)                                                     \
  __builtin_amdgcn_global_load_lds(                                                 \
      (const __attribute__((address_space(1))) unsigned int*)(gptr),                \
      (__attribute__((address_space(3))) unsigned int*)(ldsptr), 16, 0, 0)

// ===================== 256x256 8-phase GEMM (T2+T3+T4+T5) =====================
// C = A[M,K] * B[N,K]^T. 512 thr (8 waves, 2Mx4N), BK=64 (2 K-halves of 32).
// LDS 128KB: A[2buf][2kh][256r][32c] + B same. Swizzle: 16B slot p = s ^ ((r>>1)&3).
// modes: 0 bf16 [M,N]; 1 bf16 vhT per-batch; 2 fp32*scale; 3 merged proj (z<2->0, z==2->1)
__global__ __launch_bounds__(512, 2) void gemm256(
    const unsigned short* __restrict__ A,
    const unsigned short* __restrict__ B,
    void* __restrict__ C,
    int M, int N, int K, int ntn,
    long sAz, long sBz, long sCz,
    int mode, int causal_skip, float scale)
{
  // bijective XCD chunk swizzle (m204)
  const int nwg = gridDim.x, orig = blockIdx.x;
  const int qq = nwg >> 3, rr = nwg & 7, xcd = orig & 7, oo = orig >> 3;
  const int wg = (xcd < rr ? xcd * (qq + 1) : rr * (qq + 1) + (xcd - rr) * qq) + oo;
  const int mt = wg / ntn, nt = wg % ntn;
  const int z = blockIdx.y;
  if (causal_skip && nt > mt) return;
  const int emode = (mode == 3) ? (z == 2 ? 1 : 0) : mode;
  A += sAz * (long)z;
  B += sBz * (long)z;

  __shared__ __align__(16) unsigned short lds[65536];   // 128 KB: A 64KB then B 64KB

  const int tid  = threadIdx.x;
  const int wave = tid >> 6;
  const int lane = tid & 63;
  const int wr = wave >> 2, wc = wave & 3;              // 2 x 4 wave grid
  const int li = lane & 15;
  const int psw16 = (((lane >> 4) ^ ((lane >> 1) & 3)) << 4);   // swizzled 16B slot (bytes)

  f32x4 acc[8][4];
#pragma unroll
  for (int i = 0; i < 8; ++i)
#pragma unroll
    for (int jn = 0; jn < 4; ++jn) acc[i][jn] = (f32x4){0.f, 0.f, 0.f, 0.f};

  const int nkt = K / 64;   // callers guarantee nkt >= 4

  // staging: thread t -> row srow=(t>>2) (+128 for 2nd load), swizzled col slot
  const int srow = tid >> 2;
  const long scol = (long)(((tid & 3) ^ ((tid >> 3) & 3)) << 3);
  const long gA0 = (long)(mt * 256 + srow) * K + scol;
  const long gA1 = (long)(mt * 256 + 128 + srow) * K + scol;
  const long gB0 = (long)(nt * 256 + srow) * K + scol;
  const long gB1 = (long)(nt * 256 + 128 + srow) * K + scol;
  const int stw0 = wave * 1024;          // wave-uniform LDS byte base, load 0
  const int stw1 = 8192 + wave * 1024;   // load 1 (rows 128..255)

#define ABASE(c, kh) ((((c) * 2 + (kh)) * 16384))
#define BBASE(c, kh) ((65536 + ((c) * 2 + (kh)) * 16384))
#define STAGE_A(kt, kh) do { const long o = (long)(kt) * 64 + (kh) * 32;            \
    GLOAD_LDS(A + gA0 + o, (char*)lds + ABASE((kt) & 1, kh) + stw0);                \
    GLOAD_LDS(A + gA1 + o, (char*)lds + ABASE((kt) & 1, kh) + stw1); } while (0)
#define STAGE_B(kt, kh) do { const long o = (long)(kt) * 64 + (kh) * 32;            \
    GLOAD_LDS(B + gB0 + o, (char*)lds + BBASE((kt) & 1, kh) + stw0);                \
    GLOAD_LDS(B + gB1 + o, (char*)lds + BBASE((kt) & 1, kh) + stw1); } while (0)
#define RD_A(c, kk, mset, mf) \
  (*(const bf16x8*)((const char*)lds + ABASE(c, kk) + (wr * 128 + (mset) * 64 + (mf) * 16 + li) * 64 + psw16))
#define RD_B(c, kk, nf) \
  (*(const bf16x8*)((const char*)lds + BBASE(c, kk) + (wc * 64 + (nf) * 16 + li) * 64 + psw16))

  // prologue: K-tile 0 fully + first 3 half-tiles of K-tile 1 (order = steady state)
  STAGE_B(0, 0); STAGE_A(0, 0); STAGE_B(0, 1); STAGE_A(0, 1);
  STAGE_B(1, 0); STAGE_A(1, 0); STAGE_B(1, 1);
  asm volatile("s_waitcnt vmcnt(6)" ::: "memory");   // K-tile 0 (oldest 8 loads) landed
  __builtin_amdgcn_s_barrier();

  bf16x8 a[4], b0[4], b1[4];
  for (int j = 0; j < nkt; ++j) {
    const int c = j & 1;

    // ---- phase 1: kk0, M-frags 0-3 ----
#pragma unroll
    for (int nf = 0; nf < 4; ++nf) b0[nf] = RD_B(c, 0, nf);
#pragma unroll
    for (int mf = 0; mf < 4; ++mf) a[mf] = RD_A(c, 0, 0, mf);
    if (j + 1 < nkt) STAGE_A(j + 1, 1);
    __builtin_amdgcn_s_barrier();
    __builtin_amdgcn_s_setprio(1);
#pragma unroll
    for (int mf = 0; mf < 4; ++mf)
#pragma unroll
      for (int nf = 0; nf < 4; ++nf)
        acc[mf][nf] = __builtin_amdgcn_mfma_f32_16x16x32_bf16(a[mf], b0[nf], acc[mf][nf], 0, 0, 0);
    __builtin_amdgcn_s_setprio(0);
    __builtin_amdgcn_s_barrier();

    // ---- phase 2: kk0, M-frags 4-7 ----
#pragma unroll
    for (int mf = 0; mf < 4; ++mf) a[mf] = RD_A(c, 0, 1, mf);
    if (j + 2 < nkt) STAGE_B(j + 2, 0);
    __builtin_amdgcn_s_barrier();
    __builtin_amdgcn_s_setprio(1);
#pragma unroll
    for (int mf = 0; mf < 4; ++mf)
#pragma unroll
      for (int nf = 0; nf < 4; ++nf)
        acc[4 + mf][nf] = __builtin_amdgcn_mfma_f32_16x16x32_bf16(a[mf], b0[nf], acc[4 + mf][nf], 0, 0, 0);
    __builtin_amdgcn_s_setprio(0);
    __builtin_amdgcn_s_barrier();

    // ---- phase 3: kk1, M-frags 0-3 ----
#pragma unroll
    for (int nf = 0; nf < 4; ++nf) b1[nf] = RD_B(c, 1, nf);
#pragma unroll
    for (int mf = 0; mf < 4; ++mf) a[mf] = RD_A(c, 1, 0, mf);
    if (j + 2 < nkt) STAGE_A(j + 2, 0);
    __builtin_amdgcn_s_barrier();
    __builtin_amdgcn_s_setprio(1);
#pragma unroll
    for (int mf = 0; mf < 4; ++mf)
#pragma unroll
      for (int nf = 0; nf < 4; ++nf)
        acc[mf][nf] = __builtin_amdgcn_mfma_f32_16x16x32_bf16(a[mf], b1[nf], acc[mf][nf], 0, 0, 0);
    __builtin_amdgcn_s_setprio(0);
    __builtin_amdgcn_s_barrier();

    // ---- phase 4: kk1, M-frags 4-7 ----
#pragma unroll
    for (int mf = 0; mf < 4; ++mf) a[mf] = RD_A(c, 1, 1, mf);
    if (j + 2 < nkt) STAGE_B(j + 2, 1);
    __builtin_amdgcn_s_barrier();
    __builtin_amdgcn_s_setprio(1);
#pragma unroll
    for (int mf = 0; mf < 4; ++mf)
#pragma unroll
      for (int nf = 0; nf < 4; ++nf)
        acc[4 + mf][nf] = __builtin_amdgcn_mfma_f32_16x16x32_bf16(a[mf], b1[nf], acc[4 + mf][nf], 0, 0, 0);
    __builtin_amdgcn_s_setprio(0);
    if (j + 1 < nkt) {
      if (j + 2 < nkt) { asm volatile("s_waitcnt vmcnt(6)" ::: "memory"); }
      else             { asm volatile("s_waitcnt vmcnt(0)" ::: "memory"); }
    }
    __builtin_amdgcn_s_barrier();
  }
#undef ABASE
#undef BBASE
#undef STAGE_A
#undef STAGE_B
#undef RD_A
#undef RD_B

  // ---- epilogue ----
  const int rb = mt * 256 + wr * 128;
  const int cb = nt * 256 + wc * 64;
  if (emode == 0) {
    unsigned short* Cb = (unsigned short*)C + sCz * (long)z;
#pragma unroll
    for (int mi = 0; mi < 8; ++mi)
#pragma unroll
      for (int ni = 0; ni < 4; ++ni) {
        const int row0 = rb + mi * 16 + ((lane >> 4) << 2);
        const int col  = cb + ni * 16 + (lane & 15);
#pragma unroll
        for (int jj = 0; jj < 4; ++jj)
          Cb[(long)(row0 + jj) * N + col] = f2bf(acc[mi][ni][jj]);
      }
  } else if (emode == 1) {
    unsigned short* Cb = (unsigned short*)C + sCz * (long)z;
#pragma unroll
    for (int mi = 0; mi < 8; ++mi)
#pragma unroll
      for (int ni = 0; ni < 4; ++ni) {
        const int row0 = rb + mi * 16 + ((lane >> 4) << 2);
        const int col  = cb + ni * 16 + (lane & 15);
#pragma unroll
        for (int jj = 0; jj < 4; ++jj) {
          const int row = row0 + jj;
          const int b = row >> 11, l = row & 2047;
          Cb[((long)b * N + col) * 2048 + l] = f2bf(acc[mi][ni][jj]);
        }
      }
  } else {
    float* Cf = (float*)C + sCz * (long)z;
#pragma unroll
    for (int mi = 0; mi < 8; ++mi)
#pragma unroll
      for (int ni = 0; ni < 4; ++ni) {
        const int row0 = rb + mi * 16 + ((lane >> 4) << 2);
        const int col  = cb + ni * 16 + (lane & 15);
#pragma unroll
        for (int jj = 0; jj < 4; ++jj)
          Cf[(long)(row0 + jj) * N + col] = acc[mi][ni][jj] * scale;
      }
  }
}

// ===================== 128x128 2-phase GEMM (PV / out-proj) =====================
#define BM 128
#define BN 128
#define BK 32

__global__ __launch_bounds__(256, 3) void gemm_bt(
    const unsigned short* __restrict__ A,
    const unsigned short* __restrict__ B,
    void* __restrict__ C,
    int M, int N, int K, int ntiles,
    long sAz, long sBz, long sCz,
    int mode, int causal_skip, int klimit, float scale)
{
  const int nwg  = gridDim.x;
  const int orig = blockIdx.x;
  const int qq = nwg >> 3, rr = nwg & 7, xc = orig & 7, oo = orig >> 3;
  const int wg = (xc < rr ? xc * (qq + 1) : rr * (qq + 1) + (xc - rr) * qq) + oo;
  const int mt = wg / ntiles, nt = wg % ntiles;
  const int z  = blockIdx.y;
  if (causal_skip && nt > mt) return;

  A += sAz * (long)z;
  B += sBz * (long)z;

  __shared__ __align__(16) unsigned short As[3][BM * BK];
  __shared__ __align__(16) unsigned short Bs[3][BN * BK];

  const int tid  = threadIdx.x;
  const int wave = tid >> 6;
  const int lane = tid & 63;
  const int wr = wave >> 1, wc = wave & 1;

  f32x4 acc[4][4];
#pragma unroll
  for (int i = 0; i < 4; ++i)
#pragma unroll
    for (int j = 0; j < 4; ++j) acc[i][j] = (f32x4){0.f, 0.f, 0.f, 0.f};

  int kiters = K / BK;
  if (klimit) { int kl = (mt + 1) * BM; if (kl < K) kiters = kl / BK; }

  const int r0 = tid >> 2, s0 = tid & 3;
  const int c0 = ((s0 ^ ((r0 >> 1) & 3)) << 3);
  const int r1 = r0 + 64;
  const int c1 = ((s0 ^ ((r1 >> 1) & 3)) << 3);
  const long aoff0 = (long)(mt * BM + r0) * K + c0;
  const long aoff1 = (long)(mt * BM + r1) * K + c1;
  const long boff0 = (long)(nt * BN + r0) * K + c0;
  const long boff1 = (long)(nt * BN + r1) * K + c1;
  const unsigned ldsw = wave * 1024;

#define STAGE(bi, k0)                                                     \
  do {                                                                    \
    GLOAD_LDS(A + aoff0 + (k0), (char*)&As[bi][0]    + ldsw);             \
    GLOAD_LDS(A + aoff1 + (k0), (char*)&As[bi][2048] + ldsw);             \
    GLOAD_LDS(B + boff0 + (k0), (char*)&Bs[bi][0]    + ldsw);             \
    GLOAD_LDS(B + boff1 + (k0), (char*)&Bs[bi][2048] + ldsw);             \
  } while (0)

  STAGE(0, 0);
  if (kiters > 1) STAGE(1, BK);

  int cur = 0;
  for (int kt = 0; kt < kiters; ++kt) {
    const int rem = kiters - 1 - kt;
    if (rem >= 2) {
      int sb = cur + 2; if (sb >= 3) sb -= 3;
      STAGE(sb, (kt + 2) * BK);
      asm volatile("s_waitcnt vmcnt(8)" ::: "memory");
    } else if (rem == 1) {
      asm volatile("s_waitcnt vmcnt(4)" ::: "memory");
    } else {
      asm volatile("s_waitcnt vmcnt(0)" ::: "memory");
    }
    __builtin_amdgcn_s_barrier();
    asm volatile("" ::: "memory");

    bf16x8 af[4], bfr[4];
#pragma unroll
    for (int i = 0; i < 4; ++i) {
      const int ar = wr * 64 + i * 16 + (lane & 15);
      const int as = ((lane >> 4) ^ ((ar >> 1) & 3)) << 3;
      af[i] = *(const bf16x8*)&As[cur][ar * BK + as];
      const int br = wc * 64 + i * 16 + (lane & 15);
      const int bs = ((lane >> 4) ^ ((br >> 1) & 3)) << 3;
      bfr[i] = *(const bf16x8*)&Bs[cur][br * BK + bs];
    }
#pragma unroll
    for (int mi = 0; mi < 4; ++mi)
#pragma unroll
      for (int ni = 0; ni < 4; ++ni)
        acc[mi][ni] = __builtin_amdgcn_mfma_f32_16x16x32_bf16(af[mi], bfr[ni], acc[mi][ni], 0, 0, 0);

    asm volatile("" ::: "memory");
    __builtin_amdgcn_s_barrier();
    cur = (cur == 2) ? 0 : cur + 1;
  }
#undef STAGE

  const int rb = mt * BM + wr * 64;
  const int cb = nt * BN + wc * 64;

  if (mode == 0) {
    unsigned short* Cb = (unsigned short*)C + sCz * (long)z;
#pragma unroll
    for (int mi = 0; mi < 4; ++mi)
#pragma unroll
      for (int ni = 0; ni < 4; ++ni) {
        const int row0 = rb + mi * 16 + ((lane >> 4) << 2);
        const int col  = cb + ni * 16 + (lane & 15);
#pragma unroll
        for (int j = 0; j < 4; ++j)
          Cb[(long)(row0 + j) * N + col] = f2bf(acc[mi][ni][j]);
      }
  } else {
    float* Cf = (float*)C + sCz * (long)z;
#pragma unroll
    for (int mi = 0; mi < 4; ++mi)
#pragma unroll
      for (int ni = 0; ni < 4; ++ni) {
        const int row0 = rb + mi * 16 + ((lane >> 4) << 2);
        const int col  = cb + ni * 16 + (lane & 15);
#pragma unroll
        for (int j = 0; j < 4; ++j)
          Cf[(long)(row0 + j) * N + col] = acc[mi][ni][j] * scale;
      }
  }
}

// merged fp32 -> bf16 (RNE)
__global__ __launch_bounds__(256) void convert_all(
    const float* __restrict__ q, const float* __restrict__ k, const float* __restrict__ v,
    const float* __restrict__ wq, const float* __restrict__ wk,
    const float* __restrict__ wv, const float* __restrict__ wp,
    unsigned short* __restrict__ qkv, unsigned short* __restrict__ wb)
{
  const long NQ = 8192L * 1024 / 4;
  const long NW = 1024L * 1024 / 4;
  const int blk = blockIdx.x;
  const float* src; unsigned short* dst; long n; int nb, bb;
  if (blk < 1536) {
    const int s = blk >> 9;
    src = (s == 0) ? q : (s == 1) ? k : v;
    dst = qkv + (long)s * (8192L * 1024);
    n = NQ; nb = 512; bb = blk & 511;
  } else {
    const int s = (blk - 1536) >> 6;
    src = (s == 0) ? wq : (s == 1) ? wk : (s == 2) ? wv : wp;
    dst = wb + (long)s * (1024L * 1024);
    n = NW; nb = 64; bb = (blk - 1536) & 63;
  }
  for (long i = (long)bb * 256 + threadIdx.x; i < n; i += (long)nb * 256) {
    float4 x = ((const float4*)src)[i];
    ushort4 o;
    o.x = f2bf(x.x); o.y = f2bf(x.y); o.z = f2bf(x.z); o.w = f2bf(x.w);
    ((ushort4*)dst)[i] = o;
  }
}

// single-pass causal row softmax: S fp32 -> P bf16, zeros above diagonal
__global__ __launch_bounds__(256) void softmax_causal(
    const float* __restrict__ S, unsigned short* __restrict__ P, int L)
{
  const int r = blockIdx.x;
  const int b = r >> 11, q = r & 2047;
  const float* srow = S + ((long)b * L + q) * L;
  unsigned short* prow = P + ((long)b * L + q) * L;
  const int len = q + 1;
  const int tid = threadIdx.x, lane = tid & 63, wave = tid >> 6;
  const int base = tid * 8;
  __shared__ float red[8];

  float4 x0 = ((const float4*)srow)[tid * 2];
  float4 x1 = ((const float4*)srow)[tid * 2 + 1];
  float vv[8] = {x0.x, x0.y, x0.z, x0.w, x1.x, x1.y, x1.z, x1.w};

  float m = -3.4e38f;
#pragma unroll
  for (int i = 0; i < 8; ++i) if (base + i < len) m = fmaxf(m, vv[i]);
#pragma unroll
  for (int o = 32; o; o >>= 1) m = fmaxf(m, __shfl_xor(m, o));
  if (lane == 0) red[wave] = m;
  __syncthreads();
  m = fmaxf(fmaxf(red[0], red[1]), fmaxf(red[2], red[3]));

  float p[8], s = 0.f;
#pragma unroll
  for (int i = 0; i < 8; ++i) {
    p[i] = (base + i < len) ? __expf(vv[i] - m) : 0.f;
    s += p[i];
  }
#pragma unroll
  for (int o = 32; o; o >>= 1) s += __shfl_xor(s, o);
  if (lane == 0) red[4 + wave] = s;
  __syncthreads();
  s = (red[4] + red[5]) + (red[6] + red[7]);
  const float inv = 1.f / s;

  ushort8v o16;
#pragma unroll
  for (int i = 0; i < 8; ++i) o16[i] = f2bf(p[i] * inv);
  *(ushort8v*)(prow + base) = o16;
}

extern "C" void kernel_launch(void* const* d_in, const int* in_sizes, int n_in,
                              void* d_out, int out_size, void* d_ws, size_t ws_size,
                              hipStream_t stream) {
  const float* q  = (const float*)d_in[0];
  const float* k  = (const float*)d_in[1];
  const float* v  = (const float*)d_in[2];
  const float* Wq = (const float*)d_in[3];
  const float* Wk = (const float*)d_in[4];
  const float* Wv = (const float*)d_in[5];
  const float* Wp = (const float*)d_in[6];
  float* out = (float*)d_out;

  const long D    = 1024;
  const long L    = 2048;
  const long ND   = 8192 * D;
  const long NS   = 4L * L * L;

  char* ws = (char*)d_ws;
  unsigned short* qh    = (unsigned short*)ws;
  unsigned short* kh    = qh  + ND;
  unsigned short* vhT   = kh  + ND;
  unsigned short* P     = vhT + ND;
  unsigned short* ybf   = P   + NS;
  unsigned short* wbf   = ybf + ND;
  float*          S     = (float*)(wbf + 4L * D * D);
  unsigned short* qkvbf = (unsigned short*)S;   // aliases S (dead before S written)

  // 1) convert inputs + weights to bf16
  convert_all<<<1792, 256, 0, stream>>>(q, k, v, Wq, Wk, Wv, Wp, qkvbf, wbf);

  // 2) merged projections (8-phase 256^2): qh, kh (mode 0) and vhT (mode 1)
  gemm256<<<dim3(128, 3), 512, 0, stream>>>(qkvbf, wbf, qh,
      8192, 1024, 1024, 4, ND, D * D, ND, 3, 0, 1.0f);

  // 3) S = qh * kh^T * 0.125 (8-phase 256^2), causal tile skip
  gemm256<<<dim3(64, 4), 512, 0, stream>>>(qh, kh, S,
      2048, 2048, 1024, 8, L * D, L * D, L * L, 2, 1, 0.125f);

  // 4) causal softmax -> P
  softmax_causal<<<8192, 256, 0, stream>>>(S, P, 2048);

  // 5) Y = P * vh (128^2, causal K-limit)
  gemm_bt<<<dim3(128, 4), 256, 0, stream>>>(P, vhT, ybf,
      2048, 1024, 2048, 8, L * L, D * L, L * D, 0, 0, 1, 1.0f);

  // 6) out = Y * Wproj^T (fp32, 128^2)
  gemm_bt<<<dim3(512, 1), 256, 0, stream>>>(ybf, wbf + 3 * D * D, out,
      8192, 1024, 1024, 8, 0, 0, 0, 2, 0, 0, 1.0f);
}